// Round 1
// baseline (509.625 us; speedup 1.0000x reference)
//
#include <hip/hip_runtime.h>

#define BLOCKS 2048
#define TPB 256

typedef float nfloat4 __attribute__((ext_vector_type(4)));

// Main pass: per-row hamming-distance histogram + per-column BCE partial sums.
//
// R5 change vs 484us baseline: (1) dropped __builtin_nontemporal_load — nt
// demotes L2 allocation and throttles the read path to ~3.3 TB/s while the
// harness's *cached* fill kernels sustain 6.66 TB/s one-directional; (2)
// 2-deep ping-pong software pipeline at 8-row (4 KiB) granularity so each
// wave never drains to vmcnt(0) between loop iterations; (3) loads grouped
// per-array into 2 KiB sequential bursts.
//
// Work unit = 8 rows = 2 chunks = 4 KiB across both arrays (4 x 1 KiB wave
// loads). Per 4-row chunk: lane k holds floats [4*(k&15) .. +3] of row
// (k>>4). (p != g) compares become wave ballots; row hamming distance =
// popcount of the row's 16-bit slice of the 4 ballot masks.
//
// BCE on exact {0,1} inputs: loss = ln2 + p*((1-g) + log1p(e^-1) - ln2).
// ln2*N is added per column at finalize.
__global__ __launch_bounds__(TPB) void hwbce_main(
    const nfloat4* __restrict__ pred, const nfloat4* __restrict__ gt,
    unsigned int* __restrict__ g_hist, float* __restrict__ g_col,
    int nunits, int nchunks)
{
    __shared__ unsigned int lhist[64];
    __shared__ float lcol[64];
    const int tid = threadIdx.x;
    if (tid < 64) { lhist[tid] = 0u; lcol[tid] = 0.0f; }
    __syncthreads();

    const int lane  = tid & 63;
    const int wid   = tid >> 6;
    const int gwave = blockIdx.x * (TPB / 64) + wid;
    const int nwav  = gridDim.x * (TPB / 64);
    const int sub   = lane & 15;
    const unsigned long long gm = 0xFFFFull << ((lane >> 4) << 4);

    const float K1 = 0.62011450695827756f;   // 1 + log1p(e^-1) - ln2

    float a0 = 0.f, a1 = 0.f, a2 = 0.f, a3 = 0.f;

#define PROC(P, G)                                                          \
    do {                                                                    \
        unsigned long long bx = __ballot((P).x != (G).x);                   \
        unsigned long long by = __ballot((P).y != (G).y);                   \
        unsigned long long bz = __ballot((P).z != (G).z);                   \
        unsigned long long bw = __ballot((P).w != (G).w);                   \
        a0 = fmaf((P).x, K1 - (G).x, a0);                                   \
        a1 = fmaf((P).y, K1 - (G).y, a1);                                   \
        a2 = fmaf((P).z, K1 - (G).z, a2);                                   \
        a3 = fmaf((P).w, K1 - (G).w, a3);                                   \
        if (sub == 0) {                                                     \
            int d = __popcll(bx & gm) + __popcll(by & gm)                   \
                  + __popcll(bz & gm) + __popcll(bw & gm);                  \
            atomicAdd(&lhist[d < 63 ? d : 63], 1u);                        \
        }                                                                   \
    } while (0)

// 8-row unit U: float4 indices U*128 + lane and U*128 + 64 + lane.
// Loads grouped per-array: 2 KiB sequential from pred, then 2 KiB from gt.
#define LOAD4(P0, P1, G0, G1, U)                                            \
    do {                                                                    \
        const int b_ = (U) * 128 + lane;                                    \
        P0 = pred[b_];  P1 = pred[b_ + 64];                                 \
        G0 = gt[b_];    G1 = gt[b_ + 64];                                   \
    } while (0)

#define PROC2A() do { PROC(pa0, ga0); PROC(pa1, ga1); } while (0)
#define PROC2B() do { PROC(pb0, gb0); PROC(pb1, gb1); } while (0)

    {
        nfloat4 pa0, pa1, ga0, ga1, pb0, pb1, gb0, gb1;
        int u = gwave;
        if (u < nunits) {
            LOAD4(pa0, pa1, ga0, ga1, u);
            int un = u + nwav;
            bool pendingA = true;
            while (un < nunits) {
                // prefetch B, consume A
                LOAD4(pb0, pb1, gb0, gb1, un);
                PROC2A();
                un += nwav;
                if (un < nunits) {
                    // prefetch A, consume B
                    LOAD4(pa0, pa1, ga0, ga1, un);
                    PROC2B();
                    un += nwav;
                } else {
                    PROC2B();
                    pendingA = false;
                    break;
                }
            }
            if (pendingA) PROC2A();
        }
    }

    // Generic single-chunk tail (empty for N=1M, BITS=64: nchunks == 2*nunits).
    for (int c = nunits * 2 + gwave; c < nchunks; c += nwav) {
        const int idx = c * 64 + lane;
        const nfloat4 p = pred[idx];
        const nfloat4 g = gt[idx];
        PROC(p, g);
    }
#undef PROC2A
#undef PROC2B
#undef LOAD4
#undef PROC

    const int col = sub * 4;
    atomicAdd(&lcol[col + 0], a0);
    atomicAdd(&lcol[col + 1], a1);
    atomicAdd(&lcol[col + 2], a2);
    atomicAdd(&lcol[col + 3], a3);

    __syncthreads();
    if (tid < 64) {
        if (lhist[tid]) atomicAdd(&g_hist[tid], lhist[tid]);
        atomicAdd(&g_col[tid], lcol[tid]);
    }
}

// Finalize: weights from histogram, weighted sum of (column sums + N*ln2), mean.
__global__ void hwbce_final(const unsigned int* __restrict__ g_hist,
                            const float* __restrict__ g_col,
                            float* __restrict__ out,
                            float n_ln2, float inv_total)
{
    __shared__ double partial[64];
    const int j = threadIdx.x;                      // 64 threads
    const float h = (float)g_hist[j];
    const float w = expf(3.0f * fminf(h, 0.51f - h));
    partial[j] = (double)w * ((double)g_col[j] + (double)n_ln2);
    __syncthreads();
    if (j == 0) {
        double s = 0.0;
        #pragma unroll
        for (int k = 0; k < 64; ++k) s += partial[k];
        out[0] = (float)(s * (double)inv_total);
    }
}

extern "C" void kernel_launch(void* const* d_in, const int* in_sizes, int n_in,
                              void* d_out, int out_size, void* d_ws, size_t ws_size,
                              hipStream_t stream)
{
    const nfloat4* pred = (const nfloat4*)d_in[0];
    const nfloat4* gt   = (const nfloat4*)d_in[1];
    float* out = (float*)d_out;

    unsigned int* g_hist = (unsigned int*)d_ws;
    float* g_col = (float*)((char*)d_ws + 64 * sizeof(unsigned int));

    const long total   = (long)in_sizes[0];         // N * 64
    const long nrows   = total / 64;
    const int  nchunks = (int)(nrows / 4);          // 4 rows per chunk
    const int  nunits  = nchunks / 2;               // 8 rows per pipelined unit

    const float n_ln2 = (float)((double)nrows * 0.69314718055994530942);

    (void)hipMemsetAsync(d_ws, 0, 64 * (sizeof(unsigned int) + sizeof(float)), stream);
    hwbce_main<<<BLOCKS, TPB, 0, stream>>>(pred, gt, g_hist, g_col, nunits, nchunks);
    hwbce_final<<<1, 64, 0, stream>>>(g_hist, g_col, out, n_ln2, 1.0f / (float)total);
}

// Round 2
// 483.757 us; speedup vs baseline: 1.0535x; 1.0535x over previous
//
#include <hip/hip_runtime.h>

#define BLOCKS 2048
#define TPB 256

typedef float nfloat4 __attribute__((ext_vector_type(4)));

// Main pass: per-row hamming-distance histogram + per-column BCE partial sums.
//
// R2 experiment: baseline (484us, nt loads, interleaved p/g order) + 2-deep
// ping-pong software pipeline at 8-row (4-load) granularity. Single-variable
// test: R1 showed cached loads regress (-25us, L1/L2 allocation overhead on a
// single-touch 512MiB stream); this round keeps __builtin_nontemporal_load
// and tests ONLY whether keeping a second 4-load batch in flight (avg ~6
// outstanding wave-loads/wave vs ~4, at unchanged 32 waves/CU occupancy)
// lifts the ~3.3 TB/s delivered read rate.
//
// Per 4-row chunk: lane k holds floats [4*(k&15) .. +3] of row (k>>4).
// (p != g) compares become wave ballots; row hamming distance = popcount of
// the row's 16-bit slice of the 4 ballot masks.
//
// BCE on exact {0,1} inputs: loss = ln2 + p*((1-g) + log1p(e^-1) - ln2).
// ln2*N is added per column at finalize.
__global__ __launch_bounds__(TPB) void hwbce_main(
    const nfloat4* __restrict__ pred, const nfloat4* __restrict__ gt,
    unsigned int* __restrict__ g_hist, float* __restrict__ g_col,
    int nunits, int nchunks)
{
    __shared__ unsigned int lhist[64];
    __shared__ float lcol[64];
    const int tid = threadIdx.x;
    if (tid < 64) { lhist[tid] = 0u; lcol[tid] = 0.0f; }
    __syncthreads();

    const int lane  = tid & 63;
    const int wid   = tid >> 6;
    const int gwave = blockIdx.x * (TPB / 64) + wid;
    const int nwav  = gridDim.x * (TPB / 64);
    const int sub   = lane & 15;
    const unsigned long long gm = 0xFFFFull << ((lane >> 4) << 4);

    const float K1 = 0.62011450695827756f;   // 1 + log1p(e^-1) - ln2

    float a0 = 0.f, a1 = 0.f, a2 = 0.f, a3 = 0.f;

#define PROC(P, G)                                                          \
    do {                                                                    \
        unsigned long long bx = __ballot((P).x != (G).x);                   \
        unsigned long long by = __ballot((P).y != (G).y);                   \
        unsigned long long bz = __ballot((P).z != (G).z);                   \
        unsigned long long bw = __ballot((P).w != (G).w);                   \
        a0 = fmaf((P).x, K1 - (G).x, a0);                                   \
        a1 = fmaf((P).y, K1 - (G).y, a1);                                   \
        a2 = fmaf((P).z, K1 - (G).z, a2);                                   \
        a3 = fmaf((P).w, K1 - (G).w, a3);                                   \
        if (sub == 0) {                                                     \
            int d = __popcll(bx & gm) + __popcll(by & gm)                   \
                  + __popcll(bz & gm) + __popcll(bw & gm);                  \
            atomicAdd(&lhist[d < 63 ? d : 63], 1u);                        \
        }                                                                   \
    } while (0)

// 8-row unit U: float4 indices U*128 + lane and U*128 + 64 + lane.
// Baseline's interleaved p,g order; nontemporal (no L1/L2 allocation).
#define LOAD4(P0, G0, P1, G1, U)                                            \
    do {                                                                    \
        const int b_ = (U) * 128 + lane;                                    \
        P0 = __builtin_nontemporal_load(&pred[b_]);                         \
        G0 = __builtin_nontemporal_load(&gt  [b_]);                         \
        P1 = __builtin_nontemporal_load(&pred[b_ + 64]);                    \
        G1 = __builtin_nontemporal_load(&gt  [b_ + 64]);                    \
    } while (0)

#define PROC2A() do { PROC(pa0, ga0); PROC(pa1, ga1); } while (0)
#define PROC2B() do { PROC(pb0, gb0); PROC(pb1, gb1); } while (0)

    {
        nfloat4 pa0, pa1, ga0, ga1, pb0, pb1, gb0, gb1;
        int u = gwave;
        if (u < nunits) {
            LOAD4(pa0, ga0, pa1, ga1, u);
            int un = u + nwav;
            bool pendingA = true;
            while (un < nunits) {
                // prefetch B, consume A
                LOAD4(pb0, gb0, pb1, gb1, un);
                PROC2A();
                un += nwav;
                if (un < nunits) {
                    // prefetch A, consume B
                    LOAD4(pa0, ga0, pa1, ga1, un);
                    PROC2B();
                    un += nwav;
                } else {
                    PROC2B();
                    pendingA = false;
                    break;
                }
            }
            if (pendingA) PROC2A();
        }
    }

    // Generic single-chunk tail (empty for N=1M, BITS=64: nchunks == 2*nunits).
    for (int c = nunits * 2 + gwave; c < nchunks; c += nwav) {
        const int idx = c * 64 + lane;
        const nfloat4 p = __builtin_nontemporal_load(&pred[idx]);
        const nfloat4 g = __builtin_nontemporal_load(&gt[idx]);
        PROC(p, g);
    }
#undef PROC2A
#undef PROC2B
#undef LOAD4
#undef PROC

    const int col = sub * 4;
    atomicAdd(&lcol[col + 0], a0);
    atomicAdd(&lcol[col + 1], a1);
    atomicAdd(&lcol[col + 2], a2);
    atomicAdd(&lcol[col + 3], a3);

    __syncthreads();
    if (tid < 64) {
        if (lhist[tid]) atomicAdd(&g_hist[tid], lhist[tid]);
        atomicAdd(&g_col[tid], lcol[tid]);
    }
}

// Finalize: weights from histogram, weighted sum of (column sums + N*ln2), mean.
__global__ void hwbce_final(const unsigned int* __restrict__ g_hist,
                            const float* __restrict__ g_col,
                            float* __restrict__ out,
                            float n_ln2, float inv_total)
{
    __shared__ double partial[64];
    const int j = threadIdx.x;                      // 64 threads
    const float h = (float)g_hist[j];
    const float w = expf(3.0f * fminf(h, 0.51f - h));
    partial[j] = (double)w * ((double)g_col[j] + (double)n_ln2);
    __syncthreads();
    if (j == 0) {
        double s = 0.0;
        #pragma unroll
        for (int k = 0; k < 64; ++k) s += partial[k];
        out[0] = (float)(s * (double)inv_total);
    }
}

extern "C" void kernel_launch(void* const* d_in, const int* in_sizes, int n_in,
                              void* d_out, int out_size, void* d_ws, size_t ws_size,
                              hipStream_t stream)
{
    const nfloat4* pred = (const nfloat4*)d_in[0];
    const nfloat4* gt   = (const nfloat4*)d_in[1];
    float* out = (float*)d_out;

    unsigned int* g_hist = (unsigned int*)d_ws;
    float* g_col = (float*)((char*)d_ws + 64 * sizeof(unsigned int));

    const long total   = (long)in_sizes[0];         // N * 64
    const long nrows   = total / 64;
    const int  nchunks = (int)(nrows / 4);          // 4 rows per chunk
    const int  nunits  = nchunks / 2;               // 8 rows per pipelined unit

    const float n_ln2 = (float)((double)nrows * 0.69314718055994530942);

    (void)hipMemsetAsync(d_ws, 0, 64 * (sizeof(unsigned int) + sizeof(float)), stream);
    hwbce_main<<<BLOCKS, TPB, 0, stream>>>(pred, gt, g_hist, g_col, nunits, nchunks);
    hwbce_final<<<1, 64, 0, stream>>>(g_hist, g_col, out, n_ln2, 1.0f / (float)total);
}